// Round 1
// baseline (90.893 us; speedup 1.0000x reference)
//
#include <hip/hip_runtime.h>
#include <math.h>

#define BB 256
#define TT 64
#define DD 128
#define SD 16512            // DD + DD*DD
#define NCH 86              // split-K chunks for big GEMM
#define KCH 192             // 86*192 = 16512
#define LN_EPS 1e-5f

// ---------------------------------------------------------------------------
// K1: signature. grid 512 = (batch, jhalf), block 256.
// sig[b] = [S1 (128) | S2 (128x128 row-major)]
// S2 = sum_t U_t (outer) dx_t,  U_t = 0.5*(xt[t]+xt[t+1]) - xt[0]
// ---------------------------------------------------------------------------
__global__ __launch_bounds__(256) void k_sig(const float* __restrict__ x,
                                             const float* __restrict__ tk,
                                             float* __restrict__ sig) {
    int b  = blockIdx.x >> 1;
    int jh = blockIdx.x & 1;
    int tid = threadIdx.x;
    __shared__ float tks[TT];
    __shared__ float U[63][128];    // 32256 B
    __shared__ float DXh[63][64];   // 16128 B
    const float* xb = x + (size_t)b * (TT * DD);

    if (tid < TT) tks[tid] = tk[tid];
    __syncthreads();

    // build U (full 128 cols) and DXh (this block's 64-col half)
    for (int idx = tid; idx < 63 * 128; idx += 256) {
        int t = idx >> 7, i = idx & 127;
        float a = tks[t]     * xb[t * 128 + i];
        float c = tks[t + 1] * xb[(t + 1) * 128 + i];
        float z = tks[0]     * xb[i];
        U[t][i] = 0.5f * (a + c) - z;
    }
    for (int idx = tid; idx < 63 * 64; idx += 256) {
        int t = idx >> 6, j = idx & 63;
        int jj = jh * 64 + j;
        DXh[t][j] = tks[t + 1] * xb[(t + 1) * 128 + jj] - tks[t] * xb[t * 128 + jj];
    }
    if (jh == 0 && tid < 128) {
        sig[(size_t)b * SD + tid] = tks[63] * xb[63 * 128 + tid] - tks[0] * xb[tid];
    }
    __syncthreads();

    int i0 = (tid >> 4) * 8;          // 8 rows of S2
    int j0 = (tid & 15) * 4;          // 4 cols within the 64-col half
    float acc[8][4];
    #pragma unroll
    for (int i = 0; i < 8; ++i)
        #pragma unroll
        for (int j = 0; j < 4; ++j) acc[i][j] = 0.f;

    for (int t = 0; t < 63; ++t) {
        float4 dx = *(const float4*)&DXh[t][j0];
        float4 ua = *(const float4*)&U[t][i0];
        float4 ub = *(const float4*)&U[t][i0 + 4];
        float u[8] = {ua.x, ua.y, ua.z, ua.w, ub.x, ub.y, ub.z, ub.w};
        #pragma unroll
        for (int i = 0; i < 8; ++i) {
            acc[i][0] += u[i] * dx.x;
            acc[i][1] += u[i] * dx.y;
            acc[i][2] += u[i] * dx.z;
            acc[i][3] += u[i] * dx.w;
        }
    }
    float* sp = sig + (size_t)b * SD + DD + jh * 64 + j0;
    #pragma unroll
    for (int i = 0; i < 8; ++i) {
        float4 v = make_float4(acc[i][0], acc[i][1], acc[i][2], acc[i][3]);
        *(float4*)(sp + (size_t)(i0 + i) * 128) = v;
    }
}

// ---------------------------------------------------------------------------
// K2: split-K GEMM  partial[ch][b][n] , n<128 -> sig@W2 cols, n>=128 -> sig@Ws
// grid 344 = NCH*4, block 256. Tile 128(M) x 128(N) x 192(K), 8x8 per thread.
// ---------------------------------------------------------------------------
__global__ __launch_bounds__(256) void k_gemm(const float* __restrict__ sig,
                                              const float* __restrict__ W2,
                                              const float* __restrict__ Ws,
                                              float* __restrict__ partial) {
    int bid = blockIdx.x;
    int ch = bid >> 2;
    int mn = bid & 3;
    int mt = mn >> 1, nt = mn & 1;
    const float* Wsel = nt ? Ws : W2;
    int k0 = ch * KCH;
    int tid = threadIdx.x;

    __shared__ float As[128][33];   // [row][k] padded
    __shared__ float Bs[32][128];

    int r0 = (tid >> 4) * 8;
    int c0 = (tid & 15) * 8;
    float acc[8][8];
    #pragma unroll
    for (int i = 0; i < 8; ++i)
        #pragma unroll
        for (int j = 0; j < 8; ++j) acc[i][j] = 0.f;

    for (int ks = 0; ks < KCH / 32; ++ks) {
        int kb = k0 + ks * 32;
        const float* Ag = sig + (size_t)(mt * 128) * SD + kb;
        #pragma unroll
        for (int i = 0; i < 4; ++i) {
            int idx = i * 256 + tid;          // 0..1023
            int r = idx >> 3, kq = (idx & 7) * 4;
            float4 v = *(const float4*)(Ag + (size_t)r * SD + kq);
            As[r][kq]     = v.x;
            As[r][kq + 1] = v.y;
            As[r][kq + 2] = v.z;
            As[r][kq + 3] = v.w;
        }
        #pragma unroll
        for (int i = 0; i < 4; ++i) {
            int idx = i * 256 + tid;
            int kk = idx >> 5, cq = (idx & 31) * 4;
            *(float4*)&Bs[kk][cq] = *(const float4*)(Wsel + (size_t)(kb + kk) * 128 + cq);
        }
        __syncthreads();
        #pragma unroll 4
        for (int kk = 0; kk < 32; ++kk) {
            float a[8];
            #pragma unroll
            for (int i = 0; i < 8; ++i) a[i] = As[r0 + i][kk];
            float4 b0 = *(float4*)&Bs[kk][c0];
            float4 b1 = *(float4*)&Bs[kk][c0 + 4];
            float bb[8] = {b0.x, b0.y, b0.z, b0.w, b1.x, b1.y, b1.z, b1.w};
            #pragma unroll
            for (int i = 0; i < 8; ++i)
                #pragma unroll
                for (int j = 0; j < 8; ++j) acc[i][j] += a[i] * bb[j];
        }
        __syncthreads();
    }
    float* Pp = partial + (size_t)ch * 65536 + (size_t)(mt * 128) * 256 + nt * 128;
    #pragma unroll
    for (int i = 0; i < 8; ++i) {
        #pragma unroll
        for (int jq = 0; jq < 2; ++jq) {
            float4 v = make_float4(acc[i][jq * 4], acc[i][jq * 4 + 1],
                                   acc[i][jq * 4 + 2], acc[i][jq * 4 + 3]);
            *(float4*)&Pp[(size_t)(r0 + i) * 256 + c0 + jq * 4] = v;
        }
    }
}

// ---------------------------------------------------------------------------
// K4: reduce partials + GRN tail + LN + softmax -> wts[b][128]
// grid 256 (one batch per block), block 256.
// ---------------------------------------------------------------------------
__global__ __launch_bounds__(256) void k_grn(const float* __restrict__ partial,
                                             const float* __restrict__ b2,
                                             const float* __restrict__ W1,
                                             const float* __restrict__ b1,
                                             const float* __restrict__ Wg,
                                             const float* __restrict__ bg,
                                             const float* __restrict__ Wv,
                                             const float* __restrict__ bv,
                                             const float* __restrict__ bs,
                                             const float* __restrict__ gamma,
                                             const float* __restrict__ beta,
                                             float* __restrict__ wts) {
    int b = blockIdx.x, tid = threadIdx.x;
    __shared__ float hs[128], ss[128], h2s[128];
    __shared__ float gv[2][128], red2[2][128];
    __shared__ float ys[128], es[128];

    // split-K reduction (deterministic order)
    float r = 0.f;
    const float* Pp = partial + (size_t)b * 256 + tid;
    #pragma unroll 8
    for (int ch = 0; ch < NCH; ++ch) r += Pp[(size_t)ch * 65536];

    if (tid < 128) {
        float hp = r + b2[tid];
        hs[tid] = hp > 0.f ? hp : expm1f(hp);      // elu
    } else {
        ss[tid - 128] = r + bs[tid - 128];         // skip pre-bias
    }
    __syncthreads();

    int c = tid & 127, half = tid >> 7;
    {   // h2 = h1 @ W1 + b1 (split k over halves)
        float s = 0.f;
        int kb = half * 64;
        #pragma unroll 8
        for (int k = 0; k < 64; ++k) s += hs[kb + k] * W1[(size_t)(kb + k) * 128 + c];
        red2[half][c] = s;
    }
    __syncthreads();
    if (tid < 128) h2s[tid] = red2[0][tid] + red2[1][tid] + b1[tid];
    __syncthreads();
    {   // gate (half=0) / value (half=1)
        const float* Wx = half ? Wv : Wg;
        float s = 0.f;
        #pragma unroll 8
        for (int k = 0; k < 128; ++k) s += h2s[k] * Wx[(size_t)k * 128 + c];
        gv[half][c] = s;
    }
    __syncthreads();
    if (tid < 128) {
        float g = 1.f / (1.f + expf(-(gv[0][c] + bg[c])));
        float v = gv[1][c] + bv[c];
        ys[c] = ss[c] + g * v;
    }
    __syncthreads();

    // layernorm (biased var) — every thread reduces via LDS broadcast
    float sum = 0.f, sq = 0.f;
    for (int k = 0; k < 128; ++k) { float v = ys[k]; sum += v; sq += v * v; }
    float mu = sum * (1.f / 128.f);
    float var = sq * (1.f / 128.f) - mu * mu;
    float rs = rsqrtf(var + LN_EPS);
    float yn = (ys[c] - mu) * rs * gamma[c] + beta[c];
    if (tid < 128) es[c] = yn;
    __syncthreads();
    float m = -1e30f;
    for (int k = 0; k < 128; ++k) m = fmaxf(m, es[k]);
    float e = expf(yn - m);
    __syncthreads();
    if (tid < 128) ys[c] = e;
    __syncthreads();
    float se = 0.f;
    for (int k = 0; k < 128; ++k) se += ys[k];
    if (tid < 128) wts[(size_t)b * 128 + c] = e / se;
}

// ---------------------------------------------------------------------------
// K5: out[b,t,:] = (xt[b,t,:] @ Wd + bd) * wts[b,:]
// grid 256 (batch), block 512. Tile 64x128, thread 4x4, Wd staged in 32-k subtiles.
// ---------------------------------------------------------------------------
__global__ __launch_bounds__(512) void k_out(const float* __restrict__ x,
                                             const float* __restrict__ tk,
                                             const float* __restrict__ Wd,
                                             const float* __restrict__ bd,
                                             const float* __restrict__ wts,
                                             float* __restrict__ out) {
    int b = blockIdx.x, tid = threadIdx.x;
    __shared__ float Wds[32][128];     // 16 KB per subtile
    __shared__ float xs[64][132];      // padded
    __shared__ float tks[TT];

    if (tid < TT) tks[tid] = tk[tid];
    __syncthreads();

    const float* xb = x + (size_t)b * (TT * DD);
    #pragma unroll
    for (int i = 0; i < 4; ++i) {
        int idx = i * 512 + tid;            // 0..2047 f4
        int rr = idx >> 5, cq = (idx & 31) * 4;
        float4 v = *(const float4*)(xb + (size_t)rr * 128 + cq);
        float s = tks[rr];
        v.x *= s; v.y *= s; v.z *= s; v.w *= s;
        *(float4*)&xs[rr][cq] = v;
    }

    int rg = tid >> 5, cg = tid & 31;
    int r0 = rg * 4, c0 = cg * 4;
    float acc[4][4];
    #pragma unroll
    for (int i = 0; i < 4; ++i)
        #pragma unroll
        for (int j = 0; j < 4; ++j) acc[i][j] = 0.f;

    for (int ks = 0; ks < 4; ++ks) {
        // stage Wd rows ks*32 .. +32
        #pragma unroll
        for (int i = 0; i < 2; ++i) {
            int idx = i * 512 + tid;        // 0..1023 f4
            int kk = idx >> 5, cq = (idx & 31) * 4;
            *(float4*)&Wds[kk][cq] = *(const float4*)(Wd + (size_t)(ks * 32 + kk) * 128 + cq);
        }
        __syncthreads();
        #pragma unroll 4
        for (int kk = 0; kk < 32; ++kk) {
            int k = ks * 32 + kk;
            float a[4];
            #pragma unroll
            for (int i = 0; i < 4; ++i) a[i] = xs[r0 + i][k];
            float4 bv4 = *(float4*)&Wds[kk][c0];
            #pragma unroll
            for (int i = 0; i < 4; ++i) {
                acc[i][0] += a[i] * bv4.x;
                acc[i][1] += a[i] * bv4.y;
                acc[i][2] += a[i] * bv4.z;
                acc[i][3] += a[i] * bv4.w;
            }
        }
        __syncthreads();
    }

    float4 wt4 = *(const float4*)(wts + (size_t)b * 128 + c0);
    float4 bd4 = *(const float4*)(bd + c0);
    #pragma unroll
    for (int i = 0; i < 4; ++i) {
        float4 o;
        o.x = (acc[i][0] + bd4.x) * wt4.x;
        o.y = (acc[i][1] + bd4.y) * wt4.y;
        o.z = (acc[i][2] + bd4.z) * wt4.z;
        o.w = (acc[i][3] + bd4.w) * wt4.w;
        *(float4*)(out + ((size_t)b * 64 + r0 + i) * 128 + c0) = o;
    }
}

// ---------------------------------------------------------------------------
extern "C" void kernel_launch(void* const* d_in, const int* in_sizes, int n_in,
                              void* d_out, int out_size, void* d_ws, size_t ws_size,
                              hipStream_t stream) {
    const float* inputs = (const float*)d_in[0];
    const float* tk     = (const float*)d_in[1];
    const float* Wd     = (const float*)d_in[2];
    const float* bd     = (const float*)d_in[3];
    const float* W2     = (const float*)d_in[4];
    const float* b2     = (const float*)d_in[5];
    const float* W1     = (const float*)d_in[6];
    const float* b1     = (const float*)d_in[7];
    const float* Wg     = (const float*)d_in[8];
    const float* bg     = (const float*)d_in[9];
    const float* Wv     = (const float*)d_in[10];
    const float* bv     = (const float*)d_in[11];
    const float* Ws     = (const float*)d_in[12];
    const float* bs     = (const float*)d_in[13];
    const float* gamma  = (const float*)d_in[14];
    const float* beta   = (const float*)d_in[15];
    float* out = (float*)d_out;

    float* ws = (float*)d_ws;
    float* sig     = ws;                               // 256*16512 = 4,227,072
    float* partial = ws + 4227072;                     // 86*65536  = 5,636,096
    float* wts     = ws + 4227072 + 5636096;           // 32,768
    // total 9,895,936 floats = 39.6 MB

    k_sig <<<512, 256, 0, stream>>>(inputs, tk, sig);
    k_gemm<<<NCH * 4, 256, 0, stream>>>(sig, W2, Ws, partial);
    k_grn <<<256, 256, 0, stream>>>(partial, b2, W1, b1, Wg, bg, Wv, bv, bs, gamma, beta, wts);
    k_out <<<256, 512, 0, stream>>>(inputs, tk, Wd, bd, wts, out);
}

// Round 2
// 63.921 us; speedup vs baseline: 1.4219x; 1.4219x over previous
//
#include <hip/hip_runtime.h>
#include <math.h>

#define TT 64
#define DD 128
#define SD 16512            // DD + DD*DD
#define NCH 43              // split-K chunks for big GEMM
#define KCH 384             // 43*384 = 16512
#define LN_EPS 1e-5f

typedef __attribute__((ext_vector_type(4))) float f32x4;
typedef __attribute__((ext_vector_type(8))) short bf16x8;

__device__ __forceinline__ unsigned bfpack(float lo, float hi) {
    unsigned a = __builtin_bit_cast(unsigned, lo);
    unsigned b = __builtin_bit_cast(unsigned, hi);
    a = (a + 0x7FFFu + ((a >> 16) & 1u)) >> 16;
    b = (b + 0x7FFFu + ((b >> 16) & 1u)) >> 16;
    return a | (b << 16);
}
__device__ __forceinline__ unsigned short bf1(float x) {
    unsigned a = __builtin_bit_cast(unsigned, x);
    return (unsigned short)((a + 0x7FFFu + ((a >> 16) & 1u)) >> 16);
}

// ---------------------------------------------------------------------------
// K1: signature -> bf16. grid 512 = (batch, jhalf), block 256.
// sig[b] = [S1 (128) | S2 (128x128 row-major)]   (ushort bf16)
// S2 = sum_t U_t (outer) dx_t,  U_t = 0.5*(xt[t]+xt[t+1]) - xt[0]
// ---------------------------------------------------------------------------
__global__ __launch_bounds__(256) void k_sig(const float* __restrict__ x,
                                             const float* __restrict__ tk,
                                             unsigned short* __restrict__ sig) {
    int b  = blockIdx.x >> 1;
    int jh = blockIdx.x & 1;
    int tid = threadIdx.x;
    __shared__ float tks[TT];
    __shared__ float U[63][128];
    __shared__ float DXh[63][64];
    const float* xb = x + (size_t)b * (TT * DD);

    if (tid < TT) tks[tid] = tk[tid];
    __syncthreads();

    for (int idx = tid; idx < 63 * 128; idx += 256) {
        int t = idx >> 7, i = idx & 127;
        float a = tks[t]     * xb[t * 128 + i];
        float c = tks[t + 1] * xb[(t + 1) * 128 + i];
        float z = tks[0]     * xb[i];
        U[t][i] = 0.5f * (a + c) - z;
    }
    for (int idx = tid; idx < 63 * 64; idx += 256) {
        int t = idx >> 6, j = idx & 63;
        int jj = jh * 64 + j;
        DXh[t][j] = tks[t + 1] * xb[(t + 1) * 128 + jj] - tks[t] * xb[t * 128 + jj];
    }
    if (jh == 0 && tid < 128) {
        sig[(size_t)b * SD + tid] = bf1(tks[63] * xb[63 * 128 + tid] - tks[0] * xb[tid]);
    }
    __syncthreads();

    int i0 = (tid >> 4) * 8;
    int j0 = (tid & 15) * 4;
    float acc[8][4];
    #pragma unroll
    for (int i = 0; i < 8; ++i)
        #pragma unroll
        for (int j = 0; j < 4; ++j) acc[i][j] = 0.f;

    for (int t = 0; t < 63; ++t) {
        float4 dx = *(const float4*)&DXh[t][j0];
        float4 ua = *(const float4*)&U[t][i0];
        float4 ub = *(const float4*)&U[t][i0 + 4];
        float u[8] = {ua.x, ua.y, ua.z, ua.w, ub.x, ub.y, ub.z, ub.w};
        #pragma unroll
        for (int i = 0; i < 8; ++i) {
            acc[i][0] += u[i] * dx.x;
            acc[i][1] += u[i] * dx.y;
            acc[i][2] += u[i] * dx.z;
            acc[i][3] += u[i] * dx.w;
        }
    }
    unsigned short* sp = sig + (size_t)b * SD + DD + jh * 64 + j0;
    #pragma unroll
    for (int i = 0; i < 8; ++i) {
        uint2 wv;
        wv.x = bfpack(acc[i][0], acc[i][1]);
        wv.y = bfpack(acc[i][2], acc[i][3]);
        *(uint2*)(sp + (size_t)(i0 + i) * 128) = wv;
    }
}

// ---------------------------------------------------------------------------
// K2: bf16 MFMA split-K GEMM.
// grid 172 = NCH * {mt,nt}.  Block 256 thr = 4 waves, tile M=128 N=128 K=384.
// Wave grid 2x2, wave tile 64x64, 16x16x32 MFMA, 4x4 frags.
// A = sig (bf16, k-contig).  B = W2/Ws (f32) converted + transposed into LDS.
// partial[ch][row 256][col 256] f32; col<128 = W2 product, col>=128 = Ws.
// ---------------------------------------------------------------------------
__global__ __launch_bounds__(256) void k_gemm(const unsigned short* __restrict__ sig,
                                              const float* __restrict__ W2,
                                              const float* __restrict__ Ws,
                                              float* __restrict__ partial) {
    __shared__ unsigned short As[2][128][40];   // [row][k], pad 40 (16B-aligned rows)
    __shared__ unsigned short Bs[2][128][40];   // [col][k] (W^T, k-contig)

    // bijective XCD swizzle (m204): 4 sibling blocks of a chunk -> same XCD
    int p = blockIdx.x;                 // 0..171
    const int q = (NCH * 4) >> 3;       // 21
    const int r = (NCH * 4) & 7;        // 4
    int xc = p & 7, o = p >> 3;
    int lid = (xc < r ? xc * (q + 1) : r * (q + 1) + (xc - r) * q) + o;
    int ch = lid >> 2;
    int mt = (lid >> 1) & 1;
    int nt = lid & 1;
    const float* W = nt ? Ws : W2;

    int tid = threadIdx.x;
    int w = tid >> 6, lane = tid & 63;
    int wr = w >> 1, wc = w & 1;
    int l15 = lane & 15, lg = lane >> 4;
    int k0 = ch * KCH;

    // staging coordinates
    int arow[2], akq[2];
    #pragma unroll
    for (int i = 0; i < 2; ++i) { int idx = i * 256 + tid; arow[i] = idx >> 2; akq[i] = (idx & 3) * 8; }
    int bk2 = tid & 15;                 // k-pair index (k = 2*bk2, 2*bk2+1)
    int bc0 = (tid >> 4) * 4;           // col base (0..60), +i*64

    const unsigned short* sigB = sig + (size_t)(mt * 128) * SD;

    f32x4 acc[4][4];
    #pragma unroll
    for (int m = 0; m < 4; ++m)
        #pragma unroll
        for (int n = 0; n < 4; ++n) acc[m][n] = (f32x4){0.f, 0.f, 0.f, 0.f};

    uint4 aR[2];
    f32x4 bR[2][2];

#define LOADG(ks)                                                                  \
    {                                                                              \
        int kb = k0 + (ks) * 32;                                                   \
        _Pragma("unroll")                                                          \
        for (int i = 0; i < 2; ++i)                                                \
            aR[i] = *(const uint4*)(sigB + (size_t)arow[i] * SD + kb + akq[i]);    \
        _Pragma("unroll")                                                          \
        for (int i = 0; i < 2; ++i) {                                              \
            const float* wp = W + (size_t)(kb + 2 * bk2) * 128 + bc0 + i * 64;     \
            bR[i][0] = *(const f32x4*)wp;                                          \
            bR[i][1] = *(const f32x4*)(wp + 128);                                  \
        }                                                                          \
    }

#define WRITELDS(buf)                                                              \
    {                                                                              \
        _Pragma("unroll")                                                          \
        for (int i = 0; i < 2; ++i)                                                \
            *(uint4*)&As[buf][arow[i]][akq[i]] = aR[i];                            \
        _Pragma("unroll")                                                          \
        for (int i = 0; i < 2; ++i) {                                              \
            _Pragma("unroll")                                                      \
            for (int j = 0; j < 4; ++j) {                                          \
                unsigned u = bfpack(bR[i][0][j], bR[i][1][j]);                     \
                *(unsigned*)&Bs[buf][bc0 + i * 64 + j][2 * bk2] = u;               \
            }                                                                      \
        }                                                                          \
    }

#define COMPUTE(buf)                                                               \
    {                                                                              \
        bf16x8 af[4], bfr[4];                                                      \
        _Pragma("unroll")                                                          \
        for (int m = 0; m < 4; ++m)                                                \
            af[m] = *(const bf16x8*)&As[buf][wr * 64 + m * 16 + l15][lg * 8];      \
        _Pragma("unroll")                                                          \
        for (int n = 0; n < 4; ++n)                                                \
            bfr[n] = *(const bf16x8*)&Bs[buf][wc * 64 + n * 16 + l15][lg * 8];     \
        _Pragma("unroll")                                                          \
        for (int m = 0; m < 4; ++m)                                                \
            _Pragma("unroll")                                                      \
            for (int n = 0; n < 4; ++n)                                            \
                acc[m][n] = __builtin_amdgcn_mfma_f32_16x16x32_bf16(af[m], bfr[n], acc[m][n], 0, 0, 0); \
    }

    LOADG(0);
    WRITELDS(0);
    __syncthreads();

    #pragma unroll 2
    for (int ks = 0; ks < KCH / 32; ++ks) {
        int cur = ks & 1;
        if (ks < KCH / 32 - 1) LOADG(ks + 1);   // issue next-step global loads early
        COMPUTE(cur);
        if (ks < KCH / 32 - 1) WRITELDS(cur ^ 1);
        __syncthreads();
    }

    float* Pp = partial + (size_t)ch * 65536 + (size_t)(mt * 128) * 256 + nt * 128;
    #pragma unroll
    for (int m = 0; m < 4; ++m)
        #pragma unroll
        for (int n = 0; n < 4; ++n)
            #pragma unroll
            for (int rr = 0; rr < 4; ++rr)
                Pp[(size_t)(wr * 64 + m * 16 + lg * 4 + rr) * 256 + wc * 64 + n * 16 + l15] = acc[m][n][rr];

#undef LOADG
#undef WRITELDS
#undef COMPUTE
}

// ---------------------------------------------------------------------------
// K4: reduce partials + GRN tail + LN + softmax -> wts[b][128]
// ---------------------------------------------------------------------------
__global__ __launch_bounds__(256) void k_grn(const float* __restrict__ partial,
                                             const float* __restrict__ b2,
                                             const float* __restrict__ W1,
                                             const float* __restrict__ b1,
                                             const float* __restrict__ Wg,
                                             const float* __restrict__ bg,
                                             const float* __restrict__ Wv,
                                             const float* __restrict__ bv,
                                             const float* __restrict__ bs,
                                             const float* __restrict__ gamma,
                                             const float* __restrict__ beta,
                                             float* __restrict__ wts) {
    int b = blockIdx.x, tid = threadIdx.x;
    __shared__ float hs[128], ss[128], h2s[128];
    __shared__ float gv[2][128], red2[2][128];
    __shared__ float ys[128], es[128];

    float rsum = 0.f;
    const float* Pp = partial + (size_t)b * 256 + tid;
    #pragma unroll 8
    for (int ch = 0; ch < NCH; ++ch) rsum += Pp[(size_t)ch * 65536];

    if (tid < 128) {
        float hp = rsum + b2[tid];
        hs[tid] = hp > 0.f ? hp : expm1f(hp);
    } else {
        ss[tid - 128] = rsum + bs[tid - 128];
    }
    __syncthreads();

    int c = tid & 127, half = tid >> 7;
    {
        float s = 0.f;
        int kb = half * 64;
        #pragma unroll 8
        for (int k = 0; k < 64; ++k) s += hs[kb + k] * W1[(size_t)(kb + k) * 128 + c];
        red2[half][c] = s;
    }
    __syncthreads();
    if (tid < 128) h2s[tid] = red2[0][tid] + red2[1][tid] + b1[tid];
    __syncthreads();
    {
        const float* Wx = half ? Wv : Wg;
        float s = 0.f;
        #pragma unroll 8
        for (int k = 0; k < 128; ++k) s += h2s[k] * Wx[(size_t)k * 128 + c];
        gv[half][c] = s;
    }
    __syncthreads();
    if (tid < 128) {
        float g = 1.f / (1.f + expf(-(gv[0][c] + bg[c])));
        float v = gv[1][c] + bv[c];
        ys[c] = ss[c] + g * v;
    }
    __syncthreads();

    float sum = 0.f, sq = 0.f;
    for (int k = 0; k < 128; ++k) { float v = ys[k]; sum += v; sq += v * v; }
    float mu = sum * (1.f / 128.f);
    float var = sq * (1.f / 128.f) - mu * mu;
    float rs = rsqrtf(var + LN_EPS);
    float yn = (ys[c] - mu) * rs * gamma[c] + beta[c];
    if (tid < 128) es[c] = yn;
    __syncthreads();
    float m = -1e30f;
    for (int k = 0; k < 128; ++k) m = fmaxf(m, es[k]);
    float e = expf(yn - m);
    __syncthreads();
    if (tid < 128) ys[c] = e;
    __syncthreads();
    float se = 0.f;
    for (int k = 0; k < 128; ++k) se += ys[k];
    if (tid < 128) wts[(size_t)b * 128 + c] = e / se;
}

// ---------------------------------------------------------------------------
// K5: out[b,t,:] = (xt[b,t,:] @ Wd + bd) * wts[b,:]
// ---------------------------------------------------------------------------
__global__ __launch_bounds__(512) void k_out(const float* __restrict__ x,
                                             const float* __restrict__ tk,
                                             const float* __restrict__ Wd,
                                             const float* __restrict__ bd,
                                             const float* __restrict__ wts,
                                             float* __restrict__ out) {
    int b = blockIdx.x, tid = threadIdx.x;
    __shared__ float Wds[32][128];
    __shared__ float xs[64][132];
    __shared__ float tks[TT];

    if (tid < TT) tks[tid] = tk[tid];
    __syncthreads();

    const float* xb = x + (size_t)b * (TT * DD);
    #pragma unroll
    for (int i = 0; i < 4; ++i) {
        int idx = i * 512 + tid;
        int rr = idx >> 5, cq = (idx & 31) * 4;
        float4 v = *(const float4*)(xb + (size_t)rr * 128 + cq);
        float s = tks[rr];
        v.x *= s; v.y *= s; v.z *= s; v.w *= s;
        *(float4*)&xs[rr][cq] = v;
    }

    int rg = tid >> 5, cg = tid & 31;
    int r0 = rg * 4, c0 = cg * 4;
    float acc[4][4];
    #pragma unroll
    for (int i = 0; i < 4; ++i)
        #pragma unroll
        for (int j = 0; j < 4; ++j) acc[i][j] = 0.f;

    for (int ks = 0; ks < 4; ++ks) {
        #pragma unroll
        for (int i = 0; i < 2; ++i) {
            int idx = i * 512 + tid;
            int kk = idx >> 5, cq = (idx & 31) * 4;
            *(float4*)&Wds[kk][cq] = *(const float4*)(Wd + (size_t)(ks * 32 + kk) * 128 + cq);
        }
        __syncthreads();
        #pragma unroll 4
        for (int kk = 0; kk < 32; ++kk) {
            int k = ks * 32 + kk;
            float a[4];
            #pragma unroll
            for (int i = 0; i < 4; ++i) a[i] = xs[r0 + i][k];
            float4 bv4 = *(float4*)&Wds[kk][c0];
            #pragma unroll
            for (int i = 0; i < 4; ++i) {
                acc[i][0] += a[i] * bv4.x;
                acc[i][1] += a[i] * bv4.y;
                acc[i][2] += a[i] * bv4.z;
                acc[i][3] += a[i] * bv4.w;
            }
        }
        __syncthreads();
    }

    float4 wt4 = *(const float4*)(wts + (size_t)b * 128 + c0);
    float4 bd4 = *(const float4*)(bd + c0);
    #pragma unroll
    for (int i = 0; i < 4; ++i) {
        float4 o;
        o.x = (acc[i][0] + bd4.x) * wt4.x;
        o.y = (acc[i][1] + bd4.y) * wt4.y;
        o.z = (acc[i][2] + bd4.z) * wt4.z;
        o.w = (acc[i][3] + bd4.w) * wt4.w;
        *(float4*)(out + ((size_t)b * 64 + r0 + i) * 128 + c0) = o;
    }
}

// ---------------------------------------------------------------------------
extern "C" void kernel_launch(void* const* d_in, const int* in_sizes, int n_in,
                              void* d_out, int out_size, void* d_ws, size_t ws_size,
                              hipStream_t stream) {
    const float* inputs = (const float*)d_in[0];
    const float* tk     = (const float*)d_in[1];
    const float* Wd     = (const float*)d_in[2];
    const float* bd     = (const float*)d_in[3];
    const float* W2     = (const float*)d_in[4];
    const float* b2     = (const float*)d_in[5];
    const float* W1     = (const float*)d_in[6];
    const float* b1     = (const float*)d_in[7];
    const float* Wg     = (const float*)d_in[8];
    const float* bg     = (const float*)d_in[9];
    const float* Wv     = (const float*)d_in[10];
    const float* bv     = (const float*)d_in[11];
    const float* Ws     = (const float*)d_in[12];
    const float* bs     = (const float*)d_in[13];
    const float* gamma  = (const float*)d_in[14];
    const float* beta   = (const float*)d_in[15];
    float* out = (float*)d_out;

    unsigned short* sig = (unsigned short*)d_ws;               // 256*16512 ushort = 8,454,144 B
    float* partial = (float*)((char*)d_ws + 8454144);          // 43*65536 f32   = 11,272,192 B
    float* wts     = (float*)((char*)d_ws + 8454144 + 11272192); // 131,072 B

    k_sig <<<512, 256, 0, stream>>>(inputs, tk, sig);
    k_gemm<<<NCH * 4, 256, 0, stream>>>(sig, W2, Ws, partial);
    k_grn <<<256, 256, 0, stream>>>(partial, b2, W1, b1, Wg, bg, Wv, bv, bs, gamma, beta, wts);
    k_out <<<256, 512, 0, stream>>>(inputs, tk, Wd, bd, wts, out);
}